// Round 4
// baseline (1592.732 us; speedup 1.0000x reference)
//
#include <hip/hip_runtime.h>

#define BB 4
#define C 64
#define HW 65536
#define NN 16384

__global__ __launch_bounds__(256) void fuse_main(
    const float* __restrict__ feat2d,   // [B,64,H,W] f32
    const float* __restrict__ lf2d,     // [B,2,H,W]  f32
    const float* __restrict__ xy,       // [B,2,N]    f32
    const float* __restrict__ feat3d,   // [B,64,N]   f32
    const float* __restrict__ lf3d,     // [B,2,N]    f32
    const int* __restrict__ nn,         // [B,H,W,1]  i32
    const float* __restrict__ w1, const float* __restrict__ b1,
    const float* __restrict__ w2, const float* __restrict__ b2,
    const float* __restrict__ w3, const float* __restrict__ b3,
    const float* __restrict__ wf, const float* __restrict__ bfv,
    float* __restrict__ out)            // [B,64,H,W] f32
{
    const int p = blockIdx.x * 256 + threadIdx.x;  // pixel index h*W+w
    const int b = blockIdx.y;

    const int idx = nn[(size_t)b * HW + p];

    // gather 3D point row from native layout (4MB/batch, L2/L3-resident)
    const float* f3 = feat3d + (size_t)b * C * NN + idx;
    float g[C];
#pragma unroll
    for (int c = 0; c < C; c++) g[c] = f3[(size_t)c * NN];

    const float fl3x = lf3d[(size_t)(b * 2 + 0) * NN + idx];
    const float fl3y = lf3d[(size_t)(b * 2 + 1) * NN + idx];
    const float xyx  = xy[(size_t)(b * 2 + 0) * NN + idx];
    const float xyy  = xy[(size_t)(b * 2 + 1) * NN + idx];

    const float* f2p = feat2d + (size_t)b * C * HW + p;

    // correlation: mean over 64 channels of gathered feat3d * feat2d
    float corr = 0.f;
#pragma unroll
    for (int c = 0; c < C; c++) corr += f2p[(size_t)c * HW] * g[c];
    corr *= (1.f / 64.f);

    float xin[69];
    xin[0] = corr;
    xin[1] = xyx - (float)(p & 255);   // offset_x = xy_x - gx  (W=256)
    xin[2] = xyy - (float)(p >> 8);    // offset_y = xy_y - gy
#pragma unroll
    for (int c = 0; c < C; c++) xin[3 + c] = g[c];
    xin[67] = fl3x - lf2d[(size_t)(b * 2 + 0) * HW + p];
    xin[68] = fl3y - lf2d[(size_t)(b * 2 + 1) * HW + p];

    float x1[64];
#pragma unroll
    for (int o = 0; o < 64; o++) {
        float a = b1[o];
#pragma unroll
        for (int k = 0; k < 69; k++) a += w1[o * 69 + k] * xin[k];
        x1[o] = (a >= 0.f) ? a : 0.1f * a;
    }

    float x2[64];
#pragma unroll
    for (int o = 0; o < 64; o++) {
        float a = b2[o];
#pragma unroll
        for (int k = 0; k < 64; k++) a += w2[o * 64 + k] * x1[k];
        x2[o] = (a >= 0.f) ? a : 0.1f * a;
    }

    float x3[64];
#pragma unroll
    for (int o = 0; o < 64; o++) {
        float a = b3[o];
#pragma unroll
        for (int k = 0; k < 64; k++) a += w3[o * 64 + k] * x2[k];
        x3[o] = (a >= 0.f) ? a : 0.1f * a;
    }

    // final layer: wf @ concat(x3, feat_2d) + bf
    float acc[64];
#pragma unroll
    for (int o = 0; o < 64; o++) {
        float a = bfv[o];
#pragma unroll
        for (int k = 0; k < 64; k++) a += wf[o * 128 + k] * x3[k];
        acc[o] = a;
    }
#pragma unroll
    for (int k = 0; k < 64; k++) {
        const float f = f2p[(size_t)k * HW];  // L2-hot re-read
#pragma unroll
        for (int o = 0; o < 64; o++) acc[o] += wf[o * 128 + 64 + k] * f;
    }
#pragma unroll
    for (int o = 0; o < 64; o++) {
        float a = acc[o];
        a = (a >= 0.f) ? a : 0.1f * a;
        out[((size_t)(b * C + o)) * HW + p] = a;
    }
}

extern "C" void kernel_launch(void* const* d_in, const int* in_sizes, int n_in,
                              void* d_out, int out_size, void* d_ws, size_t ws_size,
                              hipStream_t stream)
{
    const float* xy   = (const float*)d_in[0];
    const float* f2d  = (const float*)d_in[1];
    const float* f3d  = (const float*)d_in[2];
    const float* lf2d = (const float*)d_in[3];
    const float* lf3d = (const float*)d_in[4];
    const int*   nn   = (const int*)d_in[5];
    const float* w1 = (const float*)d_in[6];
    const float* b1 = (const float*)d_in[7];
    const float* w2 = (const float*)d_in[8];
    const float* b2 = (const float*)d_in[9];
    const float* w3 = (const float*)d_in[10];
    const float* b3 = (const float*)d_in[11];
    const float* wf = (const float*)d_in[12];
    const float* bf = (const float*)d_in[13];

    fuse_main<<<dim3(HW / 256, BB), 256, 0, stream>>>(f2d, lf2d, xy, f3d, lf3d, nn,
                                                      w1, b1, w2, b2, w3, b3, wf, bf,
                                                      (float*)d_out);
}

// Round 5
// 246.623 us; speedup vs baseline: 6.4582x; 6.4582x over previous
//
#include <hip/hip_runtime.h>

#define BB 4
#define CH 64
#define HW 65536
#define NN 16384
#define NT 128
#define XPITCH 104
#define W1OFS 0
#define W2OFS 6144
#define W3OFS 10240
#define WFOFS 14336
#define FWS_BYTE 46080
#define PTAB_BYTE 49152
#define PT_ROW 160
#define WS_NEED ((size_t)PTAB_BYTE + (size_t)BB * NN * PT_ROW)

typedef __attribute__((ext_vector_type(8))) short short8;
typedef __attribute__((ext_vector_type(4))) float f32x4;

union frag_u { unsigned short u[8]; short8 v; };
union row_u  { uint4 q[4]; unsigned short u[32]; };

static __device__ __forceinline__ unsigned short f2bf(float x) {
    unsigned int u = __float_as_uint(x);
    return (unsigned short)((u + 0x7fffu + ((u >> 16) & 1u)) >> 16);
}
static __device__ __forceinline__ float bf2f(unsigned short h) {
    return __uint_as_float(((unsigned int)h) << 16);
}

// ---------------- prepass: pack weights (bf16) + f32 aux into ws ----------------
__global__ __launch_bounds__(256) void prep_w(
    const float* __restrict__ w1, const float* __restrict__ b1,
    const float* __restrict__ w2, const float* __restrict__ b2,
    const float* __restrict__ w3, const float* __restrict__ b3,
    const float* __restrict__ wf, const float* __restrict__ bf,
    unsigned short* __restrict__ wpk, float* __restrict__ fws)
{
    const int t = threadIdx.x;
    // w1 packed [64][96]; col map: 0-63 <- ref 3..66 (g), 64 <- ref 0 (corr),
    // 65,66 <- 0 (offset handled in f32), 67,68 <- ref 67,68 (flow), 69-95 <- 0
    for (int i = t; i < 64 * 96; i += 256) {
        const int m = i / 96, k = i % 96;
        float v = 0.f;
        if (k < 64) v = w1[m * 69 + 3 + k];
        else if (k == 64) v = w1[m * 69 + 0];
        else if (k == 67) v = w1[m * 69 + 67];
        else if (k == 68) v = w1[m * 69 + 68];
        wpk[W1OFS + i] = f2bf(v);
    }
    for (int i = t; i < 64 * 64; i += 256) wpk[W2OFS + i] = f2bf(w2[i]);
    for (int i = t; i < 64 * 64; i += 256) wpk[W3OFS + i] = f2bf(w3[i]);
    for (int i = t; i < 64 * 128; i += 256) wpk[WFOFS + i] = f2bf(wf[i]);
    if (t < 64) {
        fws[t]       = b1[t];
        fws[64 + t]  = b2[t];
        fws[128 + t] = b3[t];
        fws[192 + t] = bf[t];
        fws[256 + t] = w1[t * 69 + 1];   // offset-x column (f32 path)
        fws[320 + t] = w1[t * 69 + 2];   // offset-y column
    }
}

// ---------------- prepass: point table [B][N] row = 64 bf16 g + pad + 4 f32 ----------------
__global__ __launch_bounds__(256) void prep_t(
    const float* __restrict__ xy, const float* __restrict__ f3d,
    const float* __restrict__ lf3d, char* __restrict__ pt)
{
    const int gn = blockIdx.x * 256 + threadIdx.x;
    const int b = blockIdx.y;
    row_u r0, r1;
#pragma unroll
    for (int c = 0; c < 32; c++) r0.u[c] = f2bf(f3d[(size_t)(b * CH + c) * NN + gn]);
#pragma unroll
    for (int c = 0; c < 32; c++) r1.u[c] = f2bf(f3d[(size_t)(b * CH + 32 + c) * NN + gn]);
    char* row = pt + ((size_t)b * NN + gn) * PT_ROW;
    uint4* rq = (uint4*)row;
#pragma unroll
    for (int k = 0; k < 4; k++) rq[k] = r0.q[k];
#pragma unroll
    for (int k = 0; k < 4; k++) rq[4 + k] = r1.q[k];
    float4 e;
    e.x = xy[(size_t)(b * 2 + 0) * NN + gn];
    e.y = xy[(size_t)(b * 2 + 1) * NN + gn];
    e.z = lf3d[(size_t)(b * 2 + 0) * NN + gn];
    e.w = lf3d[(size_t)(b * 2 + 1) * NN + gn];
    *(float4*)(row + 144) = e;
}

// ---------------- MFMA layer core ----------------
template<int KT, int KROW, bool LO>
static __device__ __forceinline__ void layer_mfma(
    const unsigned short* __restrict__ wrow,
    const unsigned short* Xh, const unsigned short* Xl,
    int w, int ln, int q, f32x4 acc[4][2])
{
#pragma unroll
    for (int kt = 0; kt < KT; kt++) {
        const int kcol = kt * 32 + q * 8;
        short8 A[4];
#pragma unroll
        for (int mi = 0; mi < 4; mi++)
            A[mi] = *(const short8*)(wrow + (mi * 16 + ln) * KROW + kcol);
#pragma unroll
        for (int ni = 0; ni < 2; ni++) {
            const int nr = 32 * w + ni * 16 + ln;
            short8 bh = *(const short8*)(Xh + nr * XPITCH + kcol);
            short8 bl = bh;
            if (LO) bl = *(const short8*)(Xl + nr * XPITCH + kcol);
#pragma unroll
            for (int mi = 0; mi < 4; mi++) {
                acc[mi][ni] = __builtin_amdgcn_mfma_f32_16x16x32_bf16(A[mi], bh, acc[mi][ni], 0, 0, 0);
                if (LO)
                    acc[mi][ni] = __builtin_amdgcn_mfma_f32_16x16x32_bf16(A[mi], bl, acc[mi][ni], 0, 0, 0);
            }
        }
    }
}

static __device__ __forceinline__ void zero_acc(f32x4 acc[4][2]) {
#pragma unroll
    for (int mi = 0; mi < 4; mi++)
#pragma unroll
        for (int ni = 0; ni < 2; ni++)
#pragma unroll
            for (int r = 0; r < 4; r++) acc[mi][ni][r] = 0.f;
}

// epilogue: leaky(acc + bias [+ f32 offset fix]) -> X hi/lo (wave-private rows)
static __device__ __forceinline__ void epi_x(
    f32x4 acc[4][2], const float* __restrict__ fws, int bofs, bool off_fix,
    const float* offsp, unsigned short* Xh, unsigned short* Xl,
    int w, int ln, int q)
{
#pragma unroll
    for (int mi = 0; mi < 4; mi++) {
        const float4 bias = *(const float4*)(fws + bofs + mi * 16 + q * 4);
        float4 wox = bias, woy = bias;
        if (off_fix) {
            wox = *(const float4*)(fws + 256 + mi * 16 + q * 4);
            woy = *(const float4*)(fws + 320 + mi * 16 + q * 4);
        }
#pragma unroll
        for (int ni = 0; ni < 2; ni++) {
            const int nr = 32 * w + ni * 16 + ln;
            float ox = 0.f, oy = 0.f;
            if (off_fix) { ox = offsp[nr]; oy = offsp[NT + nr]; }
            unsigned int hh0 = 0, hh1 = 0, ll0 = 0, ll1 = 0;
#pragma unroll
            for (int r = 0; r < 4; r++) {
                float a = acc[mi][ni][r] + ((const float*)&bias)[r];
                if (off_fix) a += ((const float*)&wox)[r] * ox + ((const float*)&woy)[r] * oy;
                a = fmaxf(a, 0.1f * a);
                const unsigned short hb = f2bf(a);
                const unsigned short lb = f2bf(a - bf2f(hb));
                if (r == 0) { hh0 = hb; ll0 = lb; }
                if (r == 1) { hh0 |= ((unsigned)hb) << 16; ll0 |= ((unsigned)lb) << 16; }
                if (r == 2) { hh1 = hb; ll1 = lb; }
                if (r == 3) { hh1 |= ((unsigned)hb) << 16; ll1 |= ((unsigned)lb) << 16; }
            }
            *(uint2*)&Xh[nr * XPITCH + mi * 16 + q * 4] = make_uint2(hh0, hh1);
            *(uint2*)&Xl[nr * XPITCH + mi * 16 + q * 4] = make_uint2(ll0, ll1);
        }
    }
}

// ---------------- main fused kernel ----------------
__global__ __launch_bounds__(256, 2) void fuse(
    const float* __restrict__ feat2d, const float* __restrict__ lf2d,
    const int* __restrict__ nn,
    const unsigned short* __restrict__ wpk, const float* __restrict__ fws,
    const char* __restrict__ ptab,
    float* __restrict__ out)
{
    __shared__ unsigned short Xhi[NT * XPITCH];
    __shared__ unsigned short Xlo[NT * XPITCH];
    __shared__ float corrP[2 * NT];
    __shared__ float offsS[2 * NT];
    __shared__ float fcfS[2 * NT];
    __shared__ int idxL[NT];

    const int tid = threadIdx.x;
    const int w = tid >> 6, lane = tid & 63;
    const int q = lane >> 4, ln = lane & 15;
    const int b = blockIdx.y;
    const int p0 = blockIdx.x * NT;

    if (w == 0) {
        idxL[lane] = nn[(size_t)b * HW + p0 + lane];
        idxL[64 + lane] = nn[(size_t)b * HW + p0 + 64 + lane];
    }
    __syncthreads();

    { // stage 0: wave (h = px half, cp = channel half)
        const int h = w >> 1, cp = w & 1;
        const int n = h * 64 + lane;
        const int p = p0 + n;
        const int idx = idxL[n];
        const char* prow = ptab + ((size_t)b * NN + idx) * PT_ROW;
        row_u g;
#pragma unroll
        for (int k = 0; k < 4; k++) g.q[k] = ((const uint4*)prow)[cp * 4 + k];
        float ca = 0.f;
#pragma unroll
        for (int i = 0; i < 32; i++) {
            const int c = cp * 32 + i;
            const float f = feat2d[(size_t)(b * CH + c) * HW + p];
            ca += f * bf2f(g.u[i]);
        }
        corrP[cp * NT + n] = ca;
        uint4* xp = (uint4*)&Xhi[n * XPITCH + cp * 32];
#pragma unroll
        for (int k = 0; k < 4; k++) xp[k] = g.q[k];
        if (cp == 0) {
            const float4 e = *(const float4*)(prow + 144);
            offsS[n] = e.x - (float)(p & 255);
            offsS[NT + n] = e.y - (float)(p >> 8);
            fcfS[n] = e.z - lf2d[(size_t)(b * 2 + 0) * HW + p];
            fcfS[NT + n] = e.w - lf2d[(size_t)(b * 2 + 1) * HW + p];
        }
    }
    __syncthreads();
    if ((w & 1) == 0) { // tail cols 64..95: corr, 0, 0, fcx, fcy, zeros
        const int n = (w >> 1) * 64 + lane;
        const float corr = (corrP[n] + corrP[NT + n]) * (1.0f / 64.0f);
        const unsigned short chh = f2bf(corr);
        const unsigned short xhh = f2bf(fcfS[n]);
        const unsigned short yhh = f2bf(fcfS[NT + n]);
        uint4* tp = (uint4*)&Xhi[n * XPITCH + 64];
        tp[0] = make_uint4((unsigned)chh, ((unsigned)xhh) << 16, (unsigned)yhh, 0u);
        tp[1] = make_uint4(0, 0, 0, 0);
        tp[2] = make_uint4(0, 0, 0, 0);
        tp[3] = make_uint4(0, 0, 0, 0);
    }
    __syncthreads();

    f32x4 acc[4][2];
    // L1 (K=96, X hi only; offsets via f32 rank-2 fix)
    zero_acc(acc);
    layer_mfma<3, 96, false>(wpk + W1OFS, Xhi, Xlo, w, ln, q, acc);
    epi_x(acc, fws, 0, true, offsS, Xhi, Xlo, w, ln, q);
    // L2
    zero_acc(acc);
    layer_mfma<2, 64, true>(wpk + W2OFS, Xhi, Xlo, w, ln, q, acc);
    epi_x(acc, fws, 64, false, offsS, Xhi, Xlo, w, ln, q);
    // L3
    zero_acc(acc);
    layer_mfma<2, 64, true>(wpk + W3OFS, Xhi, Xlo, w, ln, q, acc);
    epi_x(acc, fws, 128, false, offsS, Xhi, Xlo, w, ln, q);
    // Lf: k 0-63 = x3 (LDS), k 64-127 = feat2d (global, L2-hot, hi only)
    zero_acc(acc);
    layer_mfma<2, 128, true>(wpk + WFOFS, Xhi, Xlo, w, ln, q, acc);
#pragma unroll
    for (int kt = 2; kt < 4; kt++) {
        const int kcol = kt * 32 + q * 8;
        short8 A[4];
#pragma unroll
        for (int mi = 0; mi < 4; mi++)
            A[mi] = *(const short8*)(wpk + WFOFS + (mi * 16 + ln) * 128 + kcol);
#pragma unroll
        for (int ni = 0; ni < 2; ni++) {
            frag_u fh;
#pragma unroll
            for (int j = 0; j < 8; j++) {
                const int c = (kt - 2) * 32 + q * 8 + j;
                const float v = feat2d[(size_t)(b * CH + c) * HW + p0 + 32 * w + ni * 16 + ln];
                fh.u[j] = f2bf(v);
            }
#pragma unroll
            for (int mi = 0; mi < 4; mi++)
                acc[mi][ni] = __builtin_amdgcn_mfma_f32_16x16x32_bf16(A[mi], fh.v, acc[mi][ni], 0, 0, 0);
        }
    }
    // final epilogue -> out f32
#pragma unroll
    for (int mi = 0; mi < 4; mi++) {
        const float4 bias = *(const float4*)(fws + 192 + mi * 16 + q * 4);
#pragma unroll
        for (int ni = 0; ni < 2; ni++) {
#pragma unroll
            for (int r = 0; r < 4; r++) {
                float a = acc[mi][ni][r] + ((const float*)&bias)[r];
                a = fmaxf(a, 0.1f * a);
                const int m = mi * 16 + q * 4 + r;
                out[(size_t)(b * CH + m) * HW + p0 + 32 * w + ni * 16 + ln] = a;
            }
        }
    }
}

// ---------------- fallback (R4, passed): used only if ws too small ----------------
__global__ __launch_bounds__(256) void fuse_slow(
    const float* __restrict__ feat2d, const float* __restrict__ lf2d,
    const float* __restrict__ xy, const float* __restrict__ feat3d,
    const float* __restrict__ lf3d, const int* __restrict__ nn,
    const float* __restrict__ w1, const float* __restrict__ b1,
    const float* __restrict__ w2, const float* __restrict__ b2,
    const float* __restrict__ w3, const float* __restrict__ b3,
    const float* __restrict__ wf, const float* __restrict__ bfv,
    float* __restrict__ out)
{
    const int p = blockIdx.x * 256 + threadIdx.x;
    const int b = blockIdx.y;
    const int idx = nn[(size_t)b * HW + p];
    const float* f3 = feat3d + (size_t)b * CH * NN + idx;
    float g[CH];
#pragma unroll
    for (int c = 0; c < CH; c++) g[c] = f3[(size_t)c * NN];
    const float fl3x = lf3d[(size_t)(b * 2 + 0) * NN + idx];
    const float fl3y = lf3d[(size_t)(b * 2 + 1) * NN + idx];
    const float xyx = xy[(size_t)(b * 2 + 0) * NN + idx];
    const float xyy = xy[(size_t)(b * 2 + 1) * NN + idx];
    const float* f2p = feat2d + (size_t)b * CH * HW + p;
    float corr = 0.f;
#pragma unroll
    for (int c = 0; c < CH; c++) corr += f2p[(size_t)c * HW] * g[c];
    corr *= (1.f / 64.f);
    float xin[69];
    xin[0] = corr;
    xin[1] = xyx - (float)(p & 255);
    xin[2] = xyy - (float)(p >> 8);
#pragma unroll
    for (int c = 0; c < CH; c++) xin[3 + c] = g[c];
    xin[67] = fl3x - lf2d[(size_t)(b * 2 + 0) * HW + p];
    xin[68] = fl3y - lf2d[(size_t)(b * 2 + 1) * HW + p];
    float x1[64], x2[64], x3[64], accv[64];
#pragma unroll
    for (int o = 0; o < 64; o++) {
        float a = b1[o];
#pragma unroll
        for (int k = 0; k < 69; k++) a += w1[o * 69 + k] * xin[k];
        x1[o] = (a >= 0.f) ? a : 0.1f * a;
    }
#pragma unroll
    for (int o = 0; o < 64; o++) {
        float a = b2[o];
#pragma unroll
        for (int k = 0; k < 64; k++) a += w2[o * 64 + k] * x1[k];
        x2[o] = (a >= 0.f) ? a : 0.1f * a;
    }
#pragma unroll
    for (int o = 0; o < 64; o++) {
        float a = b3[o];
#pragma unroll
        for (int k = 0; k < 64; k++) a += w3[o * 64 + k] * x2[k];
        x3[o] = (a >= 0.f) ? a : 0.1f * a;
    }
#pragma unroll
    for (int o = 0; o < 64; o++) {
        float a = bfv[o];
#pragma unroll
        for (int k = 0; k < 64; k++) a += wf[o * 128 + k] * x3[k];
        accv[o] = a;
    }
#pragma unroll
    for (int k = 0; k < 64; k++) {
        const float f = f2p[(size_t)k * HW];
#pragma unroll
        for (int o = 0; o < 64; o++) accv[o] += wf[o * 128 + 64 + k] * f;
    }
#pragma unroll
    for (int o = 0; o < 64; o++) {
        float a = accv[o];
        a = (a >= 0.f) ? a : 0.1f * a;
        out[(size_t)(b * CH + o) * HW + p] = a;
    }
}

extern "C" void kernel_launch(void* const* d_in, const int* in_sizes, int n_in,
                              void* d_out, int out_size, void* d_ws, size_t ws_size,
                              hipStream_t stream)
{
    const float* xy   = (const float*)d_in[0];
    const float* f2d  = (const float*)d_in[1];
    const float* f3d  = (const float*)d_in[2];
    const float* lf2d = (const float*)d_in[3];
    const float* lf3d = (const float*)d_in[4];
    const int*   nn   = (const int*)d_in[5];
    const float* w1 = (const float*)d_in[6];
    const float* b1 = (const float*)d_in[7];
    const float* w2 = (const float*)d_in[8];
    const float* b2 = (const float*)d_in[9];
    const float* w3 = (const float*)d_in[10];
    const float* b3 = (const float*)d_in[11];
    const float* wf = (const float*)d_in[12];
    const float* bf = (const float*)d_in[13];

    if (ws_size >= WS_NEED) {
        unsigned short* wpk = (unsigned short*)d_ws;
        float* fws = (float*)((char*)d_ws + FWS_BYTE);
        char* pt = (char*)d_ws + PTAB_BYTE;
        prep_w<<<1, 256, 0, stream>>>(w1, b1, w2, b2, w3, b3, wf, bf, wpk, fws);
        prep_t<<<dim3(NN / 256, BB), 256, 0, stream>>>(xy, f3d, lf3d, pt);
        fuse<<<dim3(HW / NT, BB), 256, 0, stream>>>(f2d, lf2d, nn, wpk, fws, pt, (float*)d_out);
    } else {
        fuse_slow<<<dim3(HW / 256, BB), 256, 0, stream>>>(f2d, lf2d, xy, f3d, lf3d, nn,
                                                          w1, b1, w2, b2, w3, b3, wf, bf,
                                                          (float*)d_out);
    }
}